// Round 1
// baseline (211.555 us; speedup 1.0000x reference)
//
#include <hip/hip_runtime.h>
#include <hip/hip_bf16.h>

#define BH_N 8192
#define BH_D 128
#define BH_NC 10
#define BH_MARGIN 1.0f
#define COLSPLIT 4
#define COLSEG (BH_N / COLSPLIT)

typedef __attribute__((ext_vector_type(8))) short bf16x8;
typedef __attribute__((ext_vector_type(4))) float f32x4;

__device__ __forceinline__ unsigned short f2bf(float f) {
    unsigned u = __float_as_uint(f);
    u += 0x7fffu + ((u >> 16) & 1u);
    return (unsigned short)(u >> 16);
}

// ---------------- Kernel 1: stable counting sort by class (single block) ----------------
__global__ __launch_bounds__(256) void bh_sort(const int* __restrict__ labels,
                                               int* __restrict__ perm,
                                               int* __restrict__ labs,
                                               int* __restrict__ cstart) {
    __shared__ int lab[BH_N];          // 32 KB
    __shared__ int sbuf[BH_NC][256];   // 10 KB scan buffer
    __shared__ int cst[BH_NC + 1];
    const int t = threadIdx.x;
    for (int i = t; i < BH_N; i += 256) lab[i] = labels[i];
    __syncthreads();

    int lh[BH_NC];
#pragma unroll
    for (int c = 0; c < BH_NC; c++) lh[c] = 0;
    const int base = t * 32;
    for (int k = 0; k < 32; k++) {
        const int L = lab[base + k];
#pragma unroll
        for (int c = 0; c < BH_NC; c++) lh[c] += (L == c);
    }
    // Hillis-Steele inclusive scan across 256 threads, 10 classes in parallel
    int val[BH_NC];
#pragma unroll
    for (int c = 0; c < BH_NC; c++) val[c] = lh[c];
    for (int ofs = 1; ofs < 256; ofs <<= 1) {
#pragma unroll
        for (int c = 0; c < BH_NC; c++) sbuf[c][t] = val[c];
        __syncthreads();
        if (t >= ofs) {
#pragma unroll
            for (int c = 0; c < BH_NC; c++) val[c] += sbuf[c][t - ofs];
        }
        __syncthreads();
    }
    if (t == 255) {  // thread 255 holds class totals
        int run = 0;
#pragma unroll
        for (int c = 0; c < BH_NC; c++) { cst[c] = run; run += val[c]; }
        cst[BH_NC] = run;
#pragma unroll
        for (int c = 0; c <= BH_NC; c++) cstart[c] = cst[c];
    }
    __syncthreads();

    int run[BH_NC];
#pragma unroll
    for (int c = 0; c < BH_NC; c++) run[c] = cst[c] + (val[c] - lh[c]);  // exclusive offset
    for (int k = 0; k < 32; k++) {
        const int j = base + k;
        const int L = lab[j];
        int pos = 0;
#pragma unroll
        for (int c = 0; c < BH_NC; c++) pos += (L == c) ? run[c] : 0;
        perm[pos] = j;
        labs[pos] = L;
#pragma unroll
        for (int c = 0; c < BH_NC; c++) run[c] += (L == c);
    }
}

// ---------------- Kernel 2: permute rows into class order, fp32->bf16, row |x|^2 ----------------
__global__ __launch_bounds__(128) void bh_permute(const float* __restrict__ E,
                                                  const int* __restrict__ perm,
                                                  unsigned short* __restrict__ Es,
                                                  float* __restrict__ x2s) {
    const int spos = blockIdx.x;
    const int t = threadIdx.x;
    const int oi = perm[spos];
    const float v = E[(size_t)oi * BH_D + t];
    Es[(size_t)spos * BH_D + t] = f2bf(v);
    float s = v * v;
#pragma unroll
    for (int m = 1; m < 64; m <<= 1) s += __shfl_xor(s, m);
    __shared__ float wsum[2];
    if ((t & 63) == 0) wsum[t >> 6] = s;
    __syncthreads();
    if (t == 0) x2s[spos] = wsum[0] + wsum[1];
}

// ---------------- Kernel 3: fused gram(MFMA) + per-class sums + same-class max ----------------
// grid = (N/32) * COLSPLIT blocks, 128 threads (2 waves). Wave handles 16 sorted anchor rows
// over column range [split*COLSEG, (split+1)*COLSEG), iterated class-segment by class-segment
// so the class index c is a compile-time constant (S[c][q] stays in registers).
__global__ __launch_bounds__(128) void bh_main(const unsigned short* __restrict__ Es,
                                               const float* __restrict__ x2s,
                                               const int* __restrict__ labs,
                                               const int* __restrict__ cstart,
                                               float* __restrict__ S_part,
                                               float* __restrict__ dpos_part) {
    const int rowblk = blockIdx.x / COLSPLIT;
    const int split  = blockIdx.x % COLSPLIT;
    const int w    = threadIdx.x >> 6;
    const int lane = threadIdx.x & 63;
    const int cidx = lane & 15;   // column (and A-row) index within 16-tile
    const int g    = lane >> 4;   // k-group / accumulator row group
    const int rb   = rowblk * 32 + w * 16;
    const int colLo = split * COLSEG;
    const int colHi = colLo + COLSEG;

    int cs[BH_NC + 1];
#pragma unroll
    for (int c = 0; c <= BH_NC; c++) cs[c] = cstart[c];

    // A fragments: rows rb..rb+15, full K=128 (4 x K32 slices)
    bf16x8 afrag[4];
#pragma unroll
    for (int ks = 0; ks < 4; ks++)
        afrag[ks] = *(const bf16x8*)(Es + (size_t)(rb + cidx) * BH_D + g * 8 + ks * 32);

    float x2row[4];
    int   labrow[4];
#pragma unroll
    for (int q = 0; q < 4; q++) {
        x2row[q]  = x2s[rb + g * 4 + q];
        labrow[q] = labs[rb + g * 4 + q];
    }

    float S[BH_NC][4];
#pragma unroll
    for (int c = 0; c < BH_NC; c++)
#pragma unroll
        for (int q = 0; q < 4; q++) S[c][q] = 0.0f;
    float dpos[4];
#pragma unroll
    for (int q = 0; q < 4; q++) dpos[q] = -3.0e38f;

#pragma unroll
    for (int c = 0; c < BH_NC; c++) {
        const int lo = max(cs[c], colLo);
        const int hi = min(cs[c + 1], colHi);
        for (int jb = (lo & ~15); jb < hi; jb += 16) {
            bf16x8 bfrag[4];
#pragma unroll
            for (int ks = 0; ks < 4; ks++)
                bfrag[ks] = *(const bf16x8*)(Es + (size_t)(jb + cidx) * BH_D + g * 8 + ks * 32);
            f32x4 acc = {0.0f, 0.0f, 0.0f, 0.0f};
#pragma unroll
            for (int ks = 0; ks < 4; ks++)
                acc = __builtin_amdgcn_mfma_f32_16x16x32_bf16(afrag[ks], bfrag[ks], acc, 0, 0, 0);

            const int jcol = jb + cidx;
            const float xc = x2s[jcol];
            const bool vm = (jcol >= lo) && (jcol < hi);  // mask partial boundary chunks
#pragma unroll
            for (int q = 0; q < 4; q++) {
                float dd = fmaxf(x2row[q] + xc - 2.0f * acc[q], 0.0f);
                S[c][q] += vm ? dd : 0.0f;
                if (vm && (labrow[q] == c)) dpos[q] = fmaxf(dpos[q], dd);
            }
        }
    }

    // reduce across the 16 lanes (columns) of each row group
#pragma unroll
    for (int c = 0; c < BH_NC; c++)
#pragma unroll
        for (int q = 0; q < 4; q++)
#pragma unroll
            for (int m = 1; m < 16; m <<= 1)
                S[c][q] += __shfl_xor(S[c][q], m);
#pragma unroll
    for (int q = 0; q < 4; q++)
#pragma unroll
        for (int m = 1; m < 16; m <<= 1)
            dpos[q] = fmaxf(dpos[q], __shfl_xor(dpos[q], m));

    if (cidx == 0) {
#pragma unroll
        for (int q = 0; q < 4; q++) {
            const int row = rb + g * 4 + q;
#pragma unroll
            for (int c = 0; c < BH_NC; c++)
                S_part[((size_t)split * BH_N + row) * BH_NC + c] = S[c][q];
            dpos_part[(size_t)split * BH_N + row] = dpos[q];
        }
    }
}

// ---------------- Kernel 4: k* selection + exact fp32 d_neg + per-block loss partials ----------------
__global__ __launch_bounds__(256) void bh_select(const float* __restrict__ E,
                                                 const float* __restrict__ x2s,
                                                 const int* __restrict__ labs,
                                                 const int* __restrict__ cstart,
                                                 const int* __restrict__ perm,
                                                 const float* __restrict__ S_part,
                                                 const float* __restrict__ dpos_part,
                                                 float* __restrict__ bpart) {
    const int w = threadIdx.x >> 6;
    const int lane = threadIdx.x & 63;
    const int spos = blockIdx.x * 4 + w;  // one wave per sorted anchor

    float Sk = 0.0f;
    if (lane < BH_NC) {
#pragma unroll
        for (int h = 0; h < COLSPLIT; h++)
            Sk += S_part[((size_t)h * BH_N + spos) * BH_NC + lane];
    }
    float tv = (lane < BH_NC) ? Sk : 0.0f;
#pragma unroll
    for (int m = 1; m < 64; m <<= 1) tv += __shfl_xor(tv, m);
    const float T = tv;

    // argmin_k (T - S[k]), first occurrence on ties (matches jnp.argmin)
    float v  = (lane < BH_NC) ? (T - Sk) : 3.0e38f;
    int  idx = (lane < BH_NC) ? lane : 64;
#pragma unroll
    for (int m = 1; m < 64; m <<= 1) {
        const float ov = __shfl_xor(v, m);
        const int  oidx = __shfl_xor(idx, m);
        if (ov < v || (ov == v && oidx < idx)) { v = ov; idx = oidx; }
    }
    const int kstar = idx;

    const int a  = labs[spos];
    const int sa = cstart[a], ea = cstart[a + 1];
    const int p  = (kstar < sa) ? kstar : (ea + (kstar - sa));  // sorted pos of (k*+1)-th negative
    const int oi = perm[spos], oj = perm[p];

    // exact fp32 squared distance to the chosen negative
    float dp = E[(size_t)oi * BH_D + lane]      * E[(size_t)oj * BH_D + lane]
             + E[(size_t)oi * BH_D + 64 + lane] * E[(size_t)oj * BH_D + 64 + lane];
#pragma unroll
    for (int m = 1; m < 64; m <<= 1) dp += __shfl_xor(dp, m);
    const float dneg = fmaxf(x2s[spos] + x2s[p] - 2.0f * dp, 0.0f);

    float dposv = -3.0e38f;
#pragma unroll
    for (int h = 0; h < COLSPLIT; h++)
        dposv = fmaxf(dposv, dpos_part[(size_t)h * BH_N + spos]);

    const float loss = fmaxf(dposv - dneg + BH_MARGIN, 0.0f);

    __shared__ float ls[4];
    if (lane == 0) ls[w] = loss;
    __syncthreads();
    if (threadIdx.x == 0) bpart[blockIdx.x] = ls[0] + ls[1] + ls[2] + ls[3];
}

// ---------------- Kernel 5: final mean ----------------
__global__ __launch_bounds__(256) void bh_final(const float* __restrict__ bpart,
                                                float* __restrict__ out) {
    float s = 0.0f;
    for (int i = threadIdx.x; i < BH_N / 4; i += 256) s += bpart[i];
#pragma unroll
    for (int m = 1; m < 64; m <<= 1) s += __shfl_xor(s, m);
    __shared__ float wsum[4];
    if ((threadIdx.x & 63) == 0) wsum[threadIdx.x >> 6] = s;
    __syncthreads();
    if (threadIdx.x == 0) out[0] = (wsum[0] + wsum[1] + wsum[2] + wsum[3]) / (float)BH_N;
}

extern "C" void kernel_launch(void* const* d_in, const int* in_sizes, int n_in,
                              void* d_out, int out_size, void* d_ws, size_t ws_size,
                              hipStream_t stream) {
    const float* E = (const float*)d_in[0];
    const int* labels = (const int*)d_in[1];
    float* out = (float*)d_out;

    // workspace carve-up (Es first for 16B alignment of bf16x8 loads)
    unsigned short* Es = (unsigned short*)d_ws;                       // N*D bf16  (2 MB)
    float* S_part    = (float*)(Es + (size_t)BH_N * BH_D);            // COLSPLIT*N*NC
    float* dpos_part = S_part + (size_t)COLSPLIT * BH_N * BH_NC;      // COLSPLIT*N
    float* x2s       = dpos_part + (size_t)COLSPLIT * BH_N;           // N
    float* bpart     = x2s + BH_N;                                    // N/4
    int* perm        = (int*)(bpart + BH_N / 4);                      // N
    int* labs        = perm + BH_N;                                   // N
    int* cstart      = labs + BH_N;                                   // NC+1

    bh_sort<<<1, 256, 0, stream>>>(labels, perm, labs, cstart);
    bh_permute<<<BH_N, 128, 0, stream>>>(E, perm, Es, x2s);
    bh_main<<<(BH_N / 32) * COLSPLIT, 128, 0, stream>>>(Es, x2s, labs, cstart, S_part, dpos_part);
    bh_select<<<BH_N / 4, 256, 0, stream>>>(E, x2s, labs, cstart, perm, S_part, dpos_part, bpart);
    bh_final<<<1, 256, 0, stream>>>(bpart, out);
}

// Round 2
// 191.416 us; speedup vs baseline: 1.1052x; 1.1052x over previous
//
#include <hip/hip_runtime.h>
#include <hip/hip_bf16.h>

#define BH_N 8192
#define BH_D 128
#define BH_NC 10
#define BH_MARGIN 1.0f
#define COLSPLIT 16
#define COLSEG (BH_N / COLSPLIT)   // 512
#define ROWS_PER_BLOCK 128         // 4 waves x 32 rows

typedef __attribute__((ext_vector_type(8)))  short bf16x8;
typedef __attribute__((ext_vector_type(16))) float f32x16;

#define OFF_R(r) (((r) & 3) + 8 * ((r) >> 2))   // C/D row offset for 32x32 MFMA, reg r (plus 4*(lane>>5))

__device__ __forceinline__ unsigned short f2bf(float f) {
    unsigned u = __float_as_uint(f);
    u += 0x7fffu + ((u >> 16) & 1u);
    return (unsigned short)(u >> 16);
}

// ---------------- Kernel 1: stable counting sort by class (1024 threads, wave scans) ----------------
__global__ __launch_bounds__(1024) void bh_sort(const int* __restrict__ labels,
                                                int* __restrict__ perm,
                                                int* __restrict__ labs,
                                                int* __restrict__ cstart,
                                                float* __restrict__ out) {
    const int t = threadIdx.x;
    const int lane = t & 63, w = t >> 6;   // 16 waves
    const int4* lp = (const int4*)labels;
    const int4 a = lp[t * 2], b = lp[t * 2 + 1];
    int L[8] = {a.x, a.y, a.z, a.w, b.x, b.y, b.z, b.w};

    int lh[BH_NC];
#pragma unroll
    for (int c = 0; c < BH_NC; c++) lh[c] = 0;
#pragma unroll
    for (int k = 0; k < 8; k++) {
#pragma unroll
        for (int c = 0; c < BH_NC; c++) lh[c] += (L[k] == c);
    }
    int inc[BH_NC];
#pragma unroll
    for (int c = 0; c < BH_NC; c++) inc[c] = lh[c];
    for (int m = 1; m < 64; m <<= 1) {
#pragma unroll
        for (int c = 0; c < BH_NC; c++) {
            const int o = __shfl_up(inc[c], m);
            if (lane >= m) inc[c] += o;
        }
    }
    __shared__ int wtot[16][BH_NC];
    __shared__ int cst[BH_NC + 1];
    if (lane == 63) {
#pragma unroll
        for (int c = 0; c < BH_NC; c++) wtot[w][c] = inc[c];
    }
    __syncthreads();
    if (t == 0) {
        int run = 0;
#pragma unroll
        for (int c = 0; c < BH_NC; c++) {
            int tot = 0;
            for (int w2 = 0; w2 < 16; w2++) tot += wtot[w2][c];
            cst[c] = run; run += tot;
        }
        cst[BH_NC] = run;
#pragma unroll
        for (int c = 0; c <= BH_NC; c++) cstart[c] = cst[c];
        out[0] = 0.0f;   // zero the output accumulator (bh_select atomicAdds into it)
    }
    __syncthreads();
    int wpre[BH_NC];
#pragma unroll
    for (int c = 0; c < BH_NC; c++) {
        int s = cst[c];
        for (int w2 = 0; w2 < w; w2++) s += wtot[w2][c];
        wpre[c] = s + inc[c] - lh[c];   // exclusive start for this thread's elements
    }
#pragma unroll
    for (int k = 0; k < 8; k++) {
        const int j = t * 8 + k;
        const int Lk = L[k];
        int pos = 0;
#pragma unroll
        for (int c = 0; c < BH_NC; c++) pos += (Lk == c) ? wpre[c] : 0;
        perm[pos] = j;
        labs[pos] = Lk;
#pragma unroll
        for (int c = 0; c < BH_NC; c++) wpre[c] += (Lk == c);
    }
}

// ---------------- Kernel 2: permute rows into class order, fp32->bf16, |x|^2, zero S/dpos ----------------
__global__ __launch_bounds__(256) void bh_permute(const float* __restrict__ E,
                                                  const int* __restrict__ perm,
                                                  unsigned short* __restrict__ Es,
                                                  float* __restrict__ x2s,
                                                  int* __restrict__ SZ) {   // S + dposU zero region
    const int t = threadIdx.x;
    const int row = blockIdx.x * 8 + (t >> 5);
    const int sub = t & 31;
    const int oi = perm[row];
    const float4 v = ((const float4*)(E + (size_t)oi * BH_D))[sub];
    ushort4 h;
    h.x = f2bf(v.x); h.y = f2bf(v.y); h.z = f2bf(v.z); h.w = f2bf(v.w);
    ((ushort4*)(Es + (size_t)row * BH_D))[sub] = h;
    float s = v.x * v.x + v.y * v.y + v.z * v.z + v.w * v.w;
#pragma unroll
    for (int m = 1; m < 32; m <<= 1) s += __shfl_xor(s, m);
    if (sub == 0) x2s[row] = s;
    // zero S[N][10] + dposU[N]  (90112 ints; grid covers 262144 threads)
    const int zi = blockIdx.x * 256 + t;
    if (zi < BH_N * (BH_NC + 1)) SZ[zi] = 0;
}

// ---------------- Kernel 3: fused gram(32x32 MFMA) + per-class sums + same-class max ----------------
// 1024 blocks x 256 threads (4 waves). Wave owns 32 sorted rows, iterates its 512-col window
// class-segment by class-segment; S accumulated for the CURRENT class only, flushed by atomicAdd.
__global__ __launch_bounds__(256, 3) void bh_main(const unsigned short* __restrict__ Es,
                                                  const float* __restrict__ x2s,
                                                  const int* __restrict__ cstart,
                                                  float* __restrict__ S,      // [N][10] atomic
                                                  int* __restrict__ dposU) {  // [N] float-bits atomic
    const int rowblk = blockIdx.x / COLSPLIT;
    const int split  = blockIdx.x % COLSPLIT;
    const int lane = threadIdx.x & 63;
    const int w    = threadIdx.x >> 6;
    const int cid  = lane & 31;
    const int half = lane >> 5;
    const int rb   = rowblk * ROWS_PER_BLOCK + w * 32;
    const int rowbase = rb + 4 * half;
    const int colLo = split * COLSEG;
    const int colHi = colLo + COLSEG;

    // A fragments: rows rb..rb+31, K=128 as 8 k-slices
    bf16x8 afrag[8];
    {
        const unsigned short* arow = Es + (size_t)(rb + cid) * BH_D + half * 8;
#pragma unroll
        for (int ks = 0; ks < 8; ks++) afrag[ks] = *(const bf16x8*)(arow + ks * 16);
    }
    float xr[16];
#pragma unroll
    for (int r = 0; r < 16; r++) xr[r] = x2s[rowbase + OFF_R(r)];

    float dpos[16];
#pragma unroll
    for (int r = 0; r < 16; r++) dpos[r] = 0.0f;

    for (int c = 0; c < BH_NC; c++) {
        const int c0 = cstart[c], c1 = cstart[c + 1];
        const int lo = max(c0, colLo), hi = min(c1, colHi);
        if (lo >= hi) continue;
        const bool rowhit = (c0 < rb + 32) && (c1 > rb);
        const int rbs0 = rowbase - c0;
        const unsigned clen = (unsigned)(c1 - c0);

        float scur[16];
#pragma unroll
        for (int r = 0; r < 16; r++) scur[r] = 0.0f;

        for (int jb = (lo & ~31); jb < hi; jb += 32) {
            const int jcol = jb + cid;
            bf16x8 bfrag[8];
            const unsigned short* brow = Es + (size_t)jcol * BH_D + half * 8;
#pragma unroll
            for (int ks = 0; ks < 8; ks++) bfrag[ks] = *(const bf16x8*)(brow + ks * 16);
            f32x16 acc = {0.0f, 0.0f, 0.0f, 0.0f, 0.0f, 0.0f, 0.0f, 0.0f,
                          0.0f, 0.0f, 0.0f, 0.0f, 0.0f, 0.0f, 0.0f, 0.0f};
#pragma unroll
            for (int ks = 0; ks < 8; ks++)
                acc = __builtin_amdgcn_mfma_f32_32x32x16_bf16(afrag[ks], bfrag[ks], acc, 0, 0, 0);

            const float xc = x2s[jcol];
            const bool vm = (jcol >= lo) && (jcol < hi);
            if (rowhit) {
#pragma unroll
                for (int r = 0; r < 16; r++) {
                    const float dd  = fmaxf(fmaf(-2.0f, acc[r], xr[r] + xc), 0.0f);
                    const float ddm = vm ? dd : 0.0f;
                    scur[r] += ddm;
                    const bool inc_ = (unsigned)(rbs0 + OFF_R(r)) < clen;
                    dpos[r] = fmaxf(dpos[r], inc_ ? ddm : 0.0f);
                }
            } else {
#pragma unroll
                for (int r = 0; r < 16; r++) {
                    const float dd  = fmaxf(fmaf(-2.0f, acc[r], xr[r] + xc), 0.0f);
                    scur[r] += vm ? dd : 0.0f;
                }
            }
        }
        // flush S for class c: reduce across the 32 column-lanes, then atomicAdd
#pragma unroll
        for (int r = 0; r < 16; r++) {
#pragma unroll
            for (int m = 1; m < 32; m <<= 1) scur[r] += __shfl_xor(scur[r], m);
        }
        if (cid == 0) {
#pragma unroll
            for (int r = 0; r < 16; r++)
                atomicAdd(&S[(size_t)(rowbase + OFF_R(r)) * BH_NC + c], scur[r]);
        }
    }

    // flush dpos: reduce max across column-lanes, atomicMax on float bits (all values >= 0)
#pragma unroll
    for (int r = 0; r < 16; r++) {
#pragma unroll
        for (int m = 1; m < 32; m <<= 1) dpos[r] = fmaxf(dpos[r], __shfl_xor(dpos[r], m));
    }
    if (cid == 0) {
#pragma unroll
        for (int r = 0; r < 16; r++)
            atomicMax(&dposU[rowbase + OFF_R(r)], __float_as_int(dpos[r]));
    }
}

// ---------------- Kernel 4: k* selection + exact fp32 d_neg + atomic mean ----------------
__global__ __launch_bounds__(256) void bh_select(const float* __restrict__ E,
                                                 const float* __restrict__ x2s,
                                                 const int* __restrict__ labs,
                                                 const int* __restrict__ cstart,
                                                 const int* __restrict__ perm,
                                                 const float* __restrict__ S,
                                                 const int* __restrict__ dposU,
                                                 float* __restrict__ out) {
    const int w = threadIdx.x >> 6;
    const int lane = threadIdx.x & 63;
    const int spos = blockIdx.x * 4 + w;

    const float Sk = (lane < BH_NC) ? S[(size_t)spos * BH_NC + lane] : 0.0f;
    float tv = Sk;
#pragma unroll
    for (int m = 1; m < 64; m <<= 1) tv += __shfl_xor(tv, m);
    const float T = tv;

    float v  = (lane < BH_NC) ? (T - Sk) : 3.0e38f;
    int  idx = (lane < BH_NC) ? lane : 64;
#pragma unroll
    for (int m = 1; m < 64; m <<= 1) {
        const float ov = __shfl_xor(v, m);
        const int  oidx = __shfl_xor(idx, m);
        if (ov < v || (ov == v && oidx < idx)) { v = ov; idx = oidx; }
    }
    const int kstar = idx;

    const int a  = labs[spos];
    const int sa = cstart[a], ea = cstart[a + 1];
    const int p  = (kstar < sa) ? kstar : (ea + (kstar - sa));
    const int oi = perm[spos], oj = perm[p];

    const float2 u0 = ((const float2*)(E + (size_t)oi * BH_D))[lane];
    const float2 u1 = ((const float2*)(E + (size_t)oj * BH_D))[lane];
    float dp = u0.x * u1.x + u0.y * u1.y;
#pragma unroll
    for (int m = 1; m < 64; m <<= 1) dp += __shfl_xor(dp, m);
    const float dneg = fmaxf(x2s[spos] + x2s[p] - 2.0f * dp, 0.0f);

    const float dposv = __int_as_float(dposU[spos]);
    const float loss = fmaxf(dposv - dneg + BH_MARGIN, 0.0f);

    __shared__ float ls[4];
    if (lane == 0) ls[w] = loss;
    __syncthreads();
    if (threadIdx.x == 0)
        atomicAdd(out, (ls[0] + ls[1] + ls[2] + ls[3]) * (1.0f / (float)BH_N));
}

extern "C" void kernel_launch(void* const* d_in, const int* in_sizes, int n_in,
                              void* d_out, int out_size, void* d_ws, size_t ws_size,
                              hipStream_t stream) {
    const float* E = (const float*)d_in[0];
    const int* labels = (const int*)d_in[1];
    float* out = (float*)d_out;

    unsigned short* Es = (unsigned short*)d_ws;                 // N*D bf16 (2 MB, 16B-aligned)
    float* S     = (float*)(Es + (size_t)BH_N * BH_D);          // N*10 f32
    int*   dposU = (int*)(S + (size_t)BH_N * BH_NC);            // N (contiguous after S for zero-init)
    float* x2s   = (float*)(dposU + BH_N);                      // N
    int* perm    = (int*)(x2s + BH_N);                          // N
    int* labs    = perm + BH_N;                                 // N
    int* cstart  = labs + BH_N;                                 // NC+1

    bh_sort<<<1, 1024, 0, stream>>>(labels, perm, labs, cstart, out);
    bh_permute<<<BH_N / 8, 256, 0, stream>>>(E, perm, Es, x2s, (int*)S);
    bh_main<<<(BH_N / ROWS_PER_BLOCK) * COLSPLIT, 256, 0, stream>>>(Es, x2s, cstart, S, dposU);
    bh_select<<<BH_N / 4, 256, 0, stream>>>(E, x2s, labs, cstart, perm, S, dposU, out);
}

// Round 3
// 128.115 us; speedup vs baseline: 1.6513x; 1.4941x over previous
//
#include <hip/hip_runtime.h>
#include <hip/hip_bf16.h>

#define BH_N 8192
#define BH_D 128
#define BH_NC 10
#define BH_MARGIN 1.0f
#define NSEG 4
#define MAXTILES (BH_N / 32 + BH_NC)   // 266 upper bound on sum of per-class row-tiles

typedef __attribute__((ext_vector_type(8)))  short bf16x8;
typedef __attribute__((ext_vector_type(16))) float f32x16;

#define OFF_R(r) (((r) & 3) + 8 * ((r) >> 2))   // C/D row offset for 32x32 MFMA (plus 4*(lane>>5))

__device__ __forceinline__ unsigned short f2bf(float f) {
    unsigned u = __float_as_uint(f);
    u += 0x7fffu + ((u >> 16) & 1u);
    return (unsigned short)(u >> 16);
}

// ---------------- Kernel 1: stable counting sort by class + zero-init scratch ----------------
__global__ __launch_bounds__(1024) void bh_sort(const int* __restrict__ labels,
                                                int* __restrict__ perm,
                                                int* __restrict__ labs,
                                                int* __restrict__ cstart,
                                                int* __restrict__ zreg,   // M+sumx2+dposU
                                                float* __restrict__ out) {
    const int t = threadIdx.x;
    // zero M[1280] + sumx2[16] + dposU[8192] = 9488 ints, and the output accumulator
    for (int i = t; i < BH_NC * BH_D + 16 + BH_N; i += 1024) zreg[i] = 0;
    if (t == 0) out[0] = 0.0f;

    const int lane = t & 63, w = t >> 6;   // 16 waves
    const int4* lp = (const int4*)labels;
    const int4 a = lp[t * 2], b = lp[t * 2 + 1];
    int L[8] = {a.x, a.y, a.z, a.w, b.x, b.y, b.z, b.w};

    int lh[BH_NC];
#pragma unroll
    for (int c = 0; c < BH_NC; c++) lh[c] = 0;
#pragma unroll
    for (int k = 0; k < 8; k++) {
#pragma unroll
        for (int c = 0; c < BH_NC; c++) lh[c] += (L[k] == c);
    }
    int inc[BH_NC];
#pragma unroll
    for (int c = 0; c < BH_NC; c++) inc[c] = lh[c];
    for (int m = 1; m < 64; m <<= 1) {
#pragma unroll
        for (int c = 0; c < BH_NC; c++) {
            const int o = __shfl_up(inc[c], m);
            if (lane >= m) inc[c] += o;
        }
    }
    __shared__ int wtot[16][BH_NC];
    __shared__ int cst[BH_NC + 1];
    if (lane == 63) {
#pragma unroll
        for (int c = 0; c < BH_NC; c++) wtot[w][c] = inc[c];
    }
    __syncthreads();
    if (t == 0) {
        int run = 0;
#pragma unroll
        for (int c = 0; c < BH_NC; c++) {
            int tot = 0;
            for (int w2 = 0; w2 < 16; w2++) tot += wtot[w2][c];
            cst[c] = run; run += tot;
        }
        cst[BH_NC] = run;
#pragma unroll
        for (int c = 0; c <= BH_NC; c++) cstart[c] = cst[c];
    }
    __syncthreads();
    int wpre[BH_NC];
#pragma unroll
    for (int c = 0; c < BH_NC; c++) {
        int s = cst[c];
        for (int w2 = 0; w2 < w; w2++) s += wtot[w2][c];
        wpre[c] = s + inc[c] - lh[c];
    }
#pragma unroll
    for (int k = 0; k < 8; k++) {
        const int j = t * 8 + k;
        const int Lk = L[k];
        int pos = 0;
#pragma unroll
        for (int c = 0; c < BH_NC; c++) pos += (Lk == c) ? wpre[c] : 0;
        perm[pos] = j;
        labs[pos] = Lk;
#pragma unroll
        for (int c = 0; c < BH_NC; c++) wpre[c] += (Lk == c);
    }
}

// ---------------- Kernel 2: permute+bf16+|x|^2 + class-sum vectors M_c and sumx2_c ----------------
__global__ __launch_bounds__(256) void bh_permute(const float* __restrict__ E,
                                                  const int* __restrict__ perm,
                                                  const int* __restrict__ labs,
                                                  unsigned short* __restrict__ Es,
                                                  float* __restrict__ x2s,
                                                  float* __restrict__ M,
                                                  float* __restrict__ sumx2) {
    __shared__ float vbuf[8][132];
    __shared__ float x2r[8];
    __shared__ int lab8[8];
    const int t = threadIdx.x;
    const int r = t >> 5, sub = t & 31;
    const int row = blockIdx.x * 8 + r;
    const int oi = perm[row];
    const float4 v = ((const float4*)(E + (size_t)oi * BH_D))[sub];
    ushort4 h;
    h.x = f2bf(v.x); h.y = f2bf(v.y); h.z = f2bf(v.z); h.w = f2bf(v.w);
    ((ushort4*)(Es + (size_t)row * BH_D))[sub] = h;
    *(float4*)(&vbuf[r][sub * 4]) = v;
    float s = v.x * v.x + v.y * v.y + v.z * v.z + v.w * v.w;
#pragma unroll
    for (int m = 1; m < 32; m <<= 1) s += __shfl_xor(s, m);
    if (sub == 0) { x2s[row] = s; x2r[r] = s; lab8[r] = labs[row]; }
    __syncthreads();
    if (t < BH_D) {   // thread t owns dimension t: run-compressed atomics (rows are class-sorted)
        int c = lab8[0]; float acc = 0.0f;
#pragma unroll
        for (int rr = 0; rr < 8; rr++) {
            const int cr = lab8[rr];
            if (cr != c) { atomicAdd(&M[(size_t)c * BH_D + t], acc); acc = 0.0f; c = cr; }
            acc += vbuf[rr][t];
        }
        atomicAdd(&M[(size_t)c * BH_D + t], acc);
    } else if (t == BH_D) {
        int c = lab8[0]; float a2 = 0.0f;
#pragma unroll
        for (int rr = 0; rr < 8; rr++) {
            const int cr = lab8[rr];
            if (cr != c) { atomicAdd(&sumx2[c], a2); a2 = 0.0f; c = cr; }
            a2 += x2r[rr];
        }
        atomicAdd(&sumx2[c], a2);
    }
}

// ---------------- Kernel 3: same-class pairwise max (d_pos) — 1 wave/block, prefetched ----------------
__global__ __launch_bounds__(64) void bh_dpos(const unsigned short* __restrict__ Es,
                                              const float* __restrict__ x2s,
                                              const int* __restrict__ cstart,
                                              int* __restrict__ dposU) {
    const int tile = blockIdx.x / NSEG;
    const int seg  = blockIdx.x % NSEG;
    int cs[BH_NC + 1];
#pragma unroll
    for (int c = 0; c <= BH_NC; c++) cs[c] = cstart[c];
    int c = -1, t0 = 0, base = 0;
#pragma unroll
    for (int cc = 0; cc < BH_NC; cc++) {
        const int len = cs[cc + 1] - cs[cc];
        const int nt = (len + 31) >> 5;
        if (c < 0 && tile < base + nt) { c = cc; t0 = tile - base; }
        base += nt;
    }
    if (c < 0) return;
    const int c0 = cs[c], c1 = cs[c + 1], len = c1 - c0;
    const int rb = c0 + t0 * 32;
    const int nch = (len + 31) >> 5;
    const int per = (nch + NSEG - 1) / NSEG;
    const int jb0 = c0 + seg * per * 32;
    if (jb0 >= c1) return;
    const int jb1 = min(jb0 + per * 32, c1);

    const int lane = threadIdx.x;
    const int cid = lane & 31, half = lane >> 5;
    const int rowbase = rb + 4 * half;

    bf16x8 afrag[8];
    {
        const int ar = min(rb + cid, BH_N - 1);
        const unsigned short* arow = Es + (size_t)ar * BH_D + half * 8;
#pragma unroll
        for (int ks = 0; ks < 8; ks++) afrag[ks] = *(const bf16x8*)(arow + ks * 16);
    }
    float xr[16];
#pragma unroll
    for (int r = 0; r < 16; r++) xr[r] = x2s[min(rowbase + OFF_R(r), BH_N - 1)];

    float dpos[16];
#pragma unroll
    for (int r = 0; r < 16; r++) dpos[r] = 0.0f;

    // register double-buffered B prefetch (branchless clamped addressing)
    int jcl = min(jb0 + cid, c1 - 1);
    bf16x8 bcur[8];
    {
        const unsigned short* brow = Es + (size_t)jcl * BH_D + half * 8;
#pragma unroll
        for (int ks = 0; ks < 8; ks++) bcur[ks] = *(const bf16x8*)(brow + ks * 16);
    }
    float xc = x2s[jcl];

    for (int jb = jb0; jb < jb1; jb += 32) {
        const int jcln = min(jb + 32 + cid, c1 - 1);
        bf16x8 bnxt[8];
        {
            const unsigned short* brow = Es + (size_t)jcln * BH_D + half * 8;
#pragma unroll
            for (int ks = 0; ks < 8; ks++) bnxt[ks] = *(const bf16x8*)(brow + ks * 16);
        }
        const float xcn = x2s[jcln];

        f32x16 acc = {0.0f, 0.0f, 0.0f, 0.0f, 0.0f, 0.0f, 0.0f, 0.0f,
                      0.0f, 0.0f, 0.0f, 0.0f, 0.0f, 0.0f, 0.0f, 0.0f};
#pragma unroll
        for (int ks = 0; ks < 8; ks++)
            acc = __builtin_amdgcn_mfma_f32_32x32x16_bf16(afrag[ks], bcur[ks], acc, 0, 0, 0);

        const bool vm = (jb + cid) < jb1;
#pragma unroll
        for (int r = 0; r < 16; r++) {
            const float dd = fmaxf(fmaf(-2.0f, acc[r], xr[r] + xc), 0.0f);
            const bool rowin = (rowbase + OFF_R(r)) < c1;
            dpos[r] = fmaxf(dpos[r], (vm && rowin) ? dd : 0.0f);
        }
#pragma unroll
        for (int ks = 0; ks < 8; ks++) bcur[ks] = bnxt[ks];
        xc = xcn;
    }
#pragma unroll
    for (int r = 0; r < 16; r++) {
#pragma unroll
        for (int m = 1; m < 32; m <<= 1) dpos[r] = fmaxf(dpos[r], __shfl_xor(dpos[r], m));
    }
    if (cid == 0) {
#pragma unroll
        for (int r = 0; r < 16; r++) {
            const int row = rowbase + OFF_R(r);
            if (row < c1) atomicMax(&dposU[row], __float_as_int(dpos[r]));
        }
    }
}

// ---------------- Kernel 4: analytic S + k* + exact fp32 d_neg + mean ----------------
__global__ __launch_bounds__(256) void bh_select(const float* __restrict__ E,
                                                 const float* __restrict__ x2s,
                                                 const int* __restrict__ labs,
                                                 const int* __restrict__ cstart,
                                                 const int* __restrict__ perm,
                                                 const float* __restrict__ M,
                                                 const float* __restrict__ sumx2,
                                                 const int* __restrict__ dposU,
                                                 float* __restrict__ out) {
    const int w = threadIdx.x >> 6, lane = threadIdx.x & 63;
    const int spos = blockIdx.x * 4 + w;
    const int oi = perm[spos];
    const float2 u0 = ((const float2*)(E + (size_t)oi * BH_D))[lane];

    float dc[BH_NC];
#pragma unroll
    for (int c = 0; c < BH_NC; c++) {
        const float2 mv = ((const float2*)(M + (size_t)c * BH_D))[lane];
        dc[c] = u0.x * mv.x + u0.y * mv.y;
    }
#pragma unroll
    for (int m = 1; m < 64; m <<= 1) {
#pragma unroll
        for (int c = 0; c < BH_NC; c++) dc[c] += __shfl_xor(dc[c], m);
    }
    const float x2i = x2s[spos];
    int cs0[BH_NC + 1];
#pragma unroll
    for (int c = 0; c <= BH_NC; c++) cs0[c] = cstart[c];

    float T = 0.0f, Sk[BH_NC];
#pragma unroll
    for (int c = 0; c < BH_NC; c++) {
        const float cnt = (float)(cs0[c + 1] - cs0[c]);
        Sk[c] = cnt * x2i + sumx2[c] - 2.0f * dc[c];
        T += Sk[c];
    }
    int kstar = 0; float best = T - Sk[0];
#pragma unroll
    for (int c = 1; c < BH_NC; c++) {
        const float nd = T - Sk[c];
        if (nd < best) { best = nd; kstar = c; }
    }

    const int a  = labs[spos];
    const int sa = cs0[a], ea = cs0[a + 1];
    const int p  = (kstar < sa) ? kstar : (ea + (kstar - sa));
    const int oj = perm[p];

    const float2 u1 = ((const float2*)(E + (size_t)oj * BH_D))[lane];
    float dp = u0.x * u1.x + u0.y * u1.y;
#pragma unroll
    for (int m = 1; m < 64; m <<= 1) dp += __shfl_xor(dp, m);
    const float dneg = fmaxf(x2i + x2s[p] - 2.0f * dp, 0.0f);

    const float dposv = __int_as_float(dposU[spos]);
    const float loss = fmaxf(dposv - dneg + BH_MARGIN, 0.0f);

    __shared__ float ls[4];
    if (lane == 0) ls[w] = loss;
    __syncthreads();
    if (threadIdx.x == 0)
        atomicAdd(out, (ls[0] + ls[1] + ls[2] + ls[3]) * (1.0f / (float)BH_N));
}

extern "C" void kernel_launch(void* const* d_in, const int* in_sizes, int n_in,
                              void* d_out, int out_size, void* d_ws, size_t ws_size,
                              hipStream_t stream) {
    const float* E = (const float*)d_in[0];
    const int* labels = (const int*)d_in[1];
    float* out = (float*)d_out;

    unsigned short* Es = (unsigned short*)d_ws;                 // N*D bf16 (2 MB, 16B-aligned)
    float* x2s   = (float*)(Es + (size_t)BH_N * BH_D);          // N
    float* M     = x2s + BH_N;                                  // 10*128   (zero region start)
    float* sumx2 = M + BH_NC * BH_D;                            // 16
    int*   dposU = (int*)(sumx2 + 16);                          // N        (zero region end)
    int*   perm  = dposU + BH_N;                                // N
    int*   labs  = perm + BH_N;                                 // N
    int*   cstart= labs + BH_N;                                 // 16

    bh_sort<<<1, 1024, 0, stream>>>(labels, perm, labs, cstart, (int*)M, out);
    bh_permute<<<BH_N / 8, 256, 0, stream>>>(E, perm, labs, Es, x2s, M, sumx2);
    bh_dpos<<<MAXTILES * NSEG, 64, 0, stream>>>(Es, x2s, cstart, dposU);
    bh_select<<<BH_N / 4, 256, 0, stream>>>(E, x2s, labs, cstart, perm, M, sumx2, dposU, out);
}

// Round 4
// 106.074 us; speedup vs baseline: 1.9944x; 1.2078x over previous
//
#include <hip/hip_runtime.h>
#include <hip/hip_bf16.h>

#define BH_N 8192
#define BH_D 128
#define BH_NC 10
#define BH_MARGIN 1.0f
#define NSEG 4
#define MAXTILES (BH_N / 32 + BH_NC)   // 266 upper bound on sum of per-class row-tiles

typedef __attribute__((ext_vector_type(8)))  short bf16x8;
typedef __attribute__((ext_vector_type(16))) float f32x16;

#define OFF_R(r) (((r) & 3) + 8 * ((r) >> 2))   // C/D row offset for 32x32 MFMA (plus 4*(lane>>5))

__device__ __forceinline__ unsigned short f2bf(float f) {
    unsigned u = __float_as_uint(f);
    u += 0x7fffu + ((u >> 16) & 1u);
    return (unsigned short)(u >> 16);
}
__device__ __forceinline__ float bf2f(short h) {
    return __uint_as_float(((unsigned)(unsigned short)h) << 16);
}

// ---------------- Kernel 1: stable counting sort by class + zero-init scratch ----------------
__global__ __launch_bounds__(1024) void bh_sort(const int* __restrict__ labels,
                                                int* __restrict__ perm,
                                                int* __restrict__ labs,
                                                int* __restrict__ cstart,
                                                int* __restrict__ zreg,   // M+sumx2+dposU
                                                float* __restrict__ out) {
    const int t = threadIdx.x;
    // zero M[1280] + sumx2[16] + dposU[8192] = 9488 ints, and the output accumulator
    for (int i = t; i < BH_NC * BH_D + 16 + BH_N; i += 1024) zreg[i] = 0;
    if (t == 0) out[0] = 0.0f;

    const int lane = t & 63, w = t >> 6;   // 16 waves
    const int4* lp = (const int4*)labels;
    const int4 a = lp[t * 2], b = lp[t * 2 + 1];
    int L[8] = {a.x, a.y, a.z, a.w, b.x, b.y, b.z, b.w};

    int lh[BH_NC];
#pragma unroll
    for (int c = 0; c < BH_NC; c++) lh[c] = 0;
#pragma unroll
    for (int k = 0; k < 8; k++) {
#pragma unroll
        for (int c = 0; c < BH_NC; c++) lh[c] += (L[k] == c);
    }
    int inc[BH_NC];
#pragma unroll
    for (int c = 0; c < BH_NC; c++) inc[c] = lh[c];
#pragma unroll
    for (int m = 1; m < 64; m <<= 1) {
#pragma unroll
        for (int c = 0; c < BH_NC; c++) {
            const int o = __shfl_up(inc[c], m);
            if (lane >= m) inc[c] += o;
        }
    }
    __shared__ int wtot[16][BH_NC];
    __shared__ int wpref[16][BH_NC];   // exclusive prefix across waves
    __shared__ int ctot[BH_NC];
    __shared__ int cst[BH_NC + 1];
    if (lane == 63) {
#pragma unroll
        for (int c = 0; c < BH_NC; c++) wtot[w][c] = inc[c];
    }
    __syncthreads();
    if (t < BH_NC) {   // thread t owns class t: prefix over the 16 waves
        int run = 0;
#pragma unroll
        for (int w2 = 0; w2 < 16; w2++) { wpref[w2][t] = run; run += wtot[w2][t]; }
        ctot[t] = run;
    }
    __syncthreads();
    if (t == 0) {
        int run = 0;
#pragma unroll
        for (int c = 0; c < BH_NC; c++) { cst[c] = run; run += ctot[c]; }
        cst[BH_NC] = run;
#pragma unroll
        for (int c = 0; c <= BH_NC; c++) cstart[c] = cst[c];
    }
    __syncthreads();
    int wpre[BH_NC];
#pragma unroll
    for (int c = 0; c < BH_NC; c++) wpre[c] = cst[c] + wpref[w][c] + inc[c] - lh[c];
#pragma unroll
    for (int k = 0; k < 8; k++) {
        const int j = t * 8 + k;
        const int Lk = L[k];
        int pos = 0;
#pragma unroll
        for (int c = 0; c < BH_NC; c++) pos += (Lk == c) ? wpre[c] : 0;
        perm[pos] = j;
        labs[pos] = Lk;
#pragma unroll
        for (int c = 0; c < BH_NC; c++) wpre[c] += (Lk == c);
    }
}

// ---------------- Kernel 2: permute+bf16+|x|^2 + class-sum vectors M_c and sumx2_c ----------------
__global__ __launch_bounds__(512) void bh_permute(const float* __restrict__ E,
                                                  const int* __restrict__ perm,
                                                  const int* __restrict__ labs,
                                                  unsigned short* __restrict__ Es,
                                                  float* __restrict__ x2s,
                                                  float* __restrict__ M,
                                                  float* __restrict__ sumx2) {
    __shared__ float vbuf[16][132];
    __shared__ float x2r[16];
    __shared__ int lab16[16];
    const int t = threadIdx.x;
    const int r = t >> 5, sub = t & 31;
    const int row = blockIdx.x * 16 + r;
    const int oi = perm[row];
    const float4 v = ((const float4*)(E + (size_t)oi * BH_D))[sub];
    ushort4 h;
    h.x = f2bf(v.x); h.y = f2bf(v.y); h.z = f2bf(v.z); h.w = f2bf(v.w);
    ((ushort4*)(Es + (size_t)row * BH_D))[sub] = h;
    *(float4*)(&vbuf[r][sub * 4]) = v;
    float s = v.x * v.x + v.y * v.y + v.z * v.z + v.w * v.w;
#pragma unroll
    for (int m = 1; m < 32; m <<= 1) s += __shfl_xor(s, m);
    if (sub == 0) { x2s[row] = s; x2r[r] = s; lab16[r] = labs[row]; }
    __syncthreads();
    if (t < BH_D) {   // thread t owns dimension t: run-compressed atomics (rows are class-sorted)
        int c = lab16[0]; float acc = 0.0f;
#pragma unroll
        for (int rr = 0; rr < 16; rr++) {
            const int cr = lab16[rr];
            if (cr != c) { atomicAdd(&M[(size_t)c * BH_D + t], acc); acc = 0.0f; c = cr; }
            acc += vbuf[rr][t];
        }
        atomicAdd(&M[(size_t)c * BH_D + t], acc);
    } else if (t == BH_D) {
        int c = lab16[0]; float a2 = 0.0f;
#pragma unroll
        for (int rr = 0; rr < 16; rr++) {
            const int cr = lab16[rr];
            if (cr != c) { atomicAdd(&sumx2[c], a2); a2 = 0.0f; c = cr; }
            a2 += x2r[rr];
        }
        atomicAdd(&sumx2[c], a2);
    }
}

// ---------------- Kernel 3: same-class pairwise max (d_pos) — 1 wave/block, prefetched ----------------
__global__ __launch_bounds__(64) void bh_dpos(const unsigned short* __restrict__ Es,
                                              const float* __restrict__ x2s,
                                              const int* __restrict__ cstart,
                                              int* __restrict__ dposU) {
    const int tile = blockIdx.x / NSEG;
    const int seg  = blockIdx.x % NSEG;
    int cs[BH_NC + 1];
#pragma unroll
    for (int c = 0; c <= BH_NC; c++) cs[c] = cstart[c];
    int c = -1, t0 = 0, base = 0;
#pragma unroll
    for (int cc = 0; cc < BH_NC; cc++) {
        const int len = cs[cc + 1] - cs[cc];
        const int nt = (len + 31) >> 5;
        if (c < 0 && tile < base + nt) { c = cc; t0 = tile - base; }
        base += nt;
    }
    if (c < 0) return;
    const int c0 = cs[c], c1 = cs[c + 1], len = c1 - c0;
    const int rb = c0 + t0 * 32;
    const int nch = (len + 31) >> 5;
    const int per = (nch + NSEG - 1) / NSEG;
    const int jb0 = c0 + seg * per * 32;
    if (jb0 >= c1) return;
    const int jb1 = min(jb0 + per * 32, c1);

    const int lane = threadIdx.x;
    const int cid = lane & 31, half = lane >> 5;
    const int rowbase = rb + 4 * half;

    bf16x8 afrag[8];
    {
        const int ar = min(rb + cid, BH_N - 1);
        const unsigned short* arow = Es + (size_t)ar * BH_D + half * 8;
#pragma unroll
        for (int ks = 0; ks < 8; ks++) afrag[ks] = *(const bf16x8*)(arow + ks * 16);
    }
    float xr[16];
#pragma unroll
    for (int r = 0; r < 16; r++) xr[r] = x2s[min(rowbase + OFF_R(r), BH_N - 1)];

    float dpos[16];
#pragma unroll
    for (int r = 0; r < 16; r++) dpos[r] = 0.0f;

    // register double-buffered B prefetch (branchless clamped addressing)
    int jcl = min(jb0 + cid, c1 - 1);
    bf16x8 bcur[8];
    {
        const unsigned short* brow = Es + (size_t)jcl * BH_D + half * 8;
#pragma unroll
        for (int ks = 0; ks < 8; ks++) bcur[ks] = *(const bf16x8*)(brow + ks * 16);
    }
    float xc = x2s[jcl];

    for (int jb = jb0; jb < jb1; jb += 32) {
        const int jcln = min(jb + 32 + cid, c1 - 1);
        bf16x8 bnxt[8];
        {
            const unsigned short* brow = Es + (size_t)jcln * BH_D + half * 8;
#pragma unroll
            for (int ks = 0; ks < 8; ks++) bnxt[ks] = *(const bf16x8*)(brow + ks * 16);
        }
        const float xcn = x2s[jcln];

        f32x16 acc = {0.0f, 0.0f, 0.0f, 0.0f, 0.0f, 0.0f, 0.0f, 0.0f,
                      0.0f, 0.0f, 0.0f, 0.0f, 0.0f, 0.0f, 0.0f, 0.0f};
#pragma unroll
        for (int ks = 0; ks < 8; ks++)
            acc = __builtin_amdgcn_mfma_f32_32x32x16_bf16(afrag[ks], bcur[ks], acc, 0, 0, 0);

        const bool vm = (jb + cid) < jb1;
#pragma unroll
        for (int r = 0; r < 16; r++) {
            const float dd = fmaxf(fmaf(-2.0f, acc[r], xr[r] + xc), 0.0f);
            const bool rowin = (rowbase + OFF_R(r)) < c1;
            dpos[r] = fmaxf(dpos[r], (vm && rowin) ? dd : 0.0f);
        }
#pragma unroll
        for (int ks = 0; ks < 8; ks++) bcur[ks] = bnxt[ks];
        xc = xcn;
    }
#pragma unroll
    for (int r = 0; r < 16; r++) {
#pragma unroll
        for (int m = 1; m < 32; m <<= 1) dpos[r] = fmaxf(dpos[r], __shfl_xor(dpos[r], m));
    }
    if (cid == 0) {
#pragma unroll
        for (int r = 0; r < 16; r++) {
            const int row = rowbase + OFF_R(r);
            if (row < c1) atomicMax(&dposU[row], __float_as_int(dpos[r]));
        }
    }
}

// ---------------- Kernel 4: per-lane anchors — analytic S, k*, d_neg, loss ----------------
// One anchor per lane, 128 blocks x 64 threads. All in sorted space (no perm indirection).
__global__ __launch_bounds__(64) void bh_select(const unsigned short* __restrict__ Es,
                                                const float* __restrict__ x2s,
                                                const int* __restrict__ cstart,
                                                const float* __restrict__ M,
                                                const float* __restrict__ sumx2,
                                                const int* __restrict__ dposU,
                                                float* __restrict__ out) {
    const int lane = threadIdx.x;
    const int spos = blockIdx.x * 64 + lane;

    int cs[BH_NC + 1];
#pragma unroll
    for (int c = 0; c <= BH_NC; c++) cs[c] = cstart[c];

    // full sorted bf16 row in registers (16 x bf16x8)
    bf16x8 u0[16];
    const unsigned short* rp = Es + (size_t)spos * BH_D;
#pragma unroll
    for (int k = 0; k < 16; k++) u0[k] = *(const bf16x8*)(rp + k * 8);

    // dc[c] = e_i . m_c   (M is tiny: 5 KB, L1-resident; same addr across lanes)
    float dc[BH_NC];
#pragma unroll
    for (int c = 0; c < BH_NC; c++) dc[c] = 0.0f;
#pragma unroll
    for (int k = 0; k < 16; k++) {
        float ef[8];
#pragma unroll
        for (int d = 0; d < 8; d++) ef[d] = bf2f(u0[k][d]);
#pragma unroll
        for (int c = 0; c < BH_NC; c++) {
            const float4 m0 = *(const float4*)(M + (size_t)c * BH_D + k * 8);
            const float4 m1 = *(const float4*)(M + (size_t)c * BH_D + k * 8 + 4);
            dc[c] += ef[0] * m0.x + ef[1] * m0.y + ef[2] * m0.z + ef[3] * m0.w
                   + ef[4] * m1.x + ef[5] * m1.y + ef[6] * m1.z + ef[7] * m1.w;
        }
    }

    const float x2i = x2s[spos];
    float T = 0.0f, Sk[BH_NC];
#pragma unroll
    for (int c = 0; c < BH_NC; c++) {
        Sk[c] = (float)(cs[c + 1] - cs[c]) * x2i + sumx2[c] - 2.0f * dc[c];
        T += Sk[c];
    }
    int kstar = 0; float best = T - Sk[0];
#pragma unroll
    for (int c = 1; c < BH_NC; c++) {
        const float nd = T - Sk[c];
        if (nd < best) { best = nd; kstar = c; }
    }

    int a = 0;
#pragma unroll
    for (int c = 1; c < BH_NC; c++) a += (spos >= cs[c]);
    const int p = (kstar < cs[a]) ? kstar : (cs[a + 1] + (kstar - cs[a]));

    // d_neg: bf16 dot of rows spos and p (both in sorted Es)
    const unsigned short* qp = Es + (size_t)p * BH_D;
    float dp = 0.0f;
#pragma unroll
    for (int k = 0; k < 16; k++) {
        const bf16x8 u1 = *(const bf16x8*)(qp + k * 8);
#pragma unroll
        for (int d = 0; d < 8; d++) dp += bf2f(u0[k][d]) * bf2f(u1[d == 0 ? 0 : d]);  // placeholder fixed below
    }
    // NOTE: the line above must index u1[d]; rewritten explicitly:
    dp = 0.0f;
#pragma unroll
    for (int k = 0; k < 16; k++) {
        const bf16x8 u1 = *(const bf16x8*)(qp + k * 8);
#pragma unroll
        for (int d = 0; d < 8; d++) dp = fmaf(bf2f(u0[k][d]), bf2f(u1[d]), dp);
    }
    const float dneg = fmaxf(x2i + x2s[p] - 2.0f * dp, 0.0f);

    const float dposv = __int_as_float(dposU[spos]);
    float loss = fmaxf(dposv - dneg + BH_MARGIN, 0.0f);
#pragma unroll
    for (int m = 1; m < 64; m <<= 1) loss += __shfl_xor(loss, m);
    if (lane == 0) atomicAdd(out, loss * (1.0f / (float)BH_N));
}

extern "C" void kernel_launch(void* const* d_in, const int* in_sizes, int n_in,
                              void* d_out, int out_size, void* d_ws, size_t ws_size,
                              hipStream_t stream) {
    const float* E = (const float*)d_in[0];
    const int* labels = (const int*)d_in[1];
    float* out = (float*)d_out;

    unsigned short* Es = (unsigned short*)d_ws;                 // N*D bf16 (2 MB, 16B-aligned)
    float* x2s   = (float*)(Es + (size_t)BH_N * BH_D);          // N
    float* M     = x2s + BH_N;                                  // 10*128   (zero region start)
    float* sumx2 = M + BH_NC * BH_D;                            // 16
    int*   dposU = (int*)(sumx2 + 16);                          // N        (zero region end)
    int*   perm  = dposU + BH_N;                                // N
    int*   labs  = perm + BH_N;                                 // N
    int*   cstart= labs + BH_N;                                 // 16

    bh_sort<<<1, 1024, 0, stream>>>(labels, perm, labs, cstart, (int*)M, out);
    bh_permute<<<BH_N / 16, 512, 0, stream>>>(E, perm, labs, Es, x2s, M, sumx2);
    bh_dpos<<<MAXTILES * NSEG, 64, 0, stream>>>(Es, x2s, cstart, dposU);
    bh_select<<<BH_N / 64, 64, 0, stream>>>(Es, x2s, cstart, M, sumx2, dposU, out);
}